// Round 1
// baseline (112.479 us; speedup 1.0000x reference)
//
#include <hip/hip_runtime.h>

// RSNA loss: pred/label [128, 8192, 10] fp32, seq_lens [128] i32 -> scalar fp32.
//
// Structure (2 dispatches, no memset, no atomics):
//   kernel 1 (128 rows x SPLIT blocks, 256 thr): masked-prefix row sums ->
//     20 floats per (row, split) written to a PRIVATE slot of row_acc
//     (plain stores; no zeroed-workspace dependency, no atomics).
//     Records are 40 B; pairs of records (80 B) are 16B-aligned, so the
//     main loop does 5x float4 per array per 2 records (16 B/lane).
//   kernel 2 (1 block, 128 thr): sum the SPLIT slots per row, per-row
//     nonlinear part (exam BCE of means, image weighting) + final
//     reduction + division -> d_out[0].
//
// Only l < seq_lens[b] is ever read -> ~half the 84 MB input traffic.

#define L_DIM 8192
#define B_DIM 128
#define C_DIM 10
#define SPLIT 8

#define IMAGE_WEIGHT 0.0736196319f

__device__ __constant__ float EXAM_W[9] = {
    0.0736196319f, 0.09202453988f, 0.1042944785f, 0.1042944785f,
    0.1877300613f, 0.06257668712f, 0.06257668712f, 0.2346625767f,
    0.0782208589f};

__global__ __launch_bounds__(256) void rsna_partial_kernel(
    const float* __restrict__ pred, const float* __restrict__ label,
    const int* __restrict__ seq_lens, float* __restrict__ row_acc) {
  const int b = blockIdx.x;  // 0..127
  const int s = blockIdx.y;  // 0..SPLIT-1
  const int len = seq_lens[b];
  // Even chunk so every chunk start is an even record index -> 16B-aligned.
  int chunk = (len + SPLIT - 1) / SPLIT;
  chunk = (chunk + 1) & ~1;
  const int start = s * chunk;
  const int end = min(start + chunk, len);
  const int n = end - start;  // may be <= 0 for tail splits of short rows

  float sp[9], sl[9];
#pragma unroll
  for (int c = 0; c < 9; ++c) {
    sp[c] = 0.0f;
    sl[c] = 0.0f;
  }
  float sy0 = 0.0f;
  float sbce = 0.0f;

  if (n > 0) {
    const int npair = n >> 1;  // full record-pairs
    const size_t base = ((size_t)b * L_DIM + (size_t)start) * C_DIM;
    const float4* p4base = reinterpret_cast<const float4*>(pred + base);
    const float4* y4base = reinterpret_cast<const float4*>(label + base);

    for (int t = (int)threadIdx.x; t < npair; t += 256) {
      const float4* p4 = p4base + (size_t)t * 5;  // 80 B = 2 records
      const float4* y4 = y4base + (size_t)t * 5;
      float p[20], y[20];
#pragma unroll
      for (int j = 0; j < 5; ++j) {
        const float4 pv = p4[j];
        const float4 yv = y4[j];
        p[4 * j + 0] = pv.x;
        p[4 * j + 1] = pv.y;
        p[4 * j + 2] = pv.z;
        p[4 * j + 3] = pv.w;
        y[4 * j + 0] = yv.x;
        y[4 * j + 1] = yv.y;
        y[4 * j + 2] = yv.z;
        y[4 * j + 3] = yv.w;
      }
#pragma unroll
      for (int c = 0; c < 9; ++c) {
        sp[c] += p[c + 1] + p[c + 11];
        sl[c] += y[c + 1] + y[c + 11];
      }
      sy0 += y[0] + y[10];
      sbce += -(y[0] * __logf(p[0]) + (1.0f - y[0]) * __logf(1.0f - p[0]));
      sbce += -(y[10] * __logf(p[10]) + (1.0f - y[10]) * __logf(1.0f - p[10]));
    }

    // Odd tail record (at most one per block): handled by thread 0.
    if ((n & 1) && threadIdx.x == 0) {
      const int l = end - 1;
      const size_t tbase = ((size_t)b * L_DIM + (size_t)l) * C_DIM;
      const float2* p2 = reinterpret_cast<const float2*>(pred + tbase);
      const float2* y2 = reinterpret_cast<const float2*>(label + tbase);
      float p[10], y[10];
#pragma unroll
      for (int i = 0; i < 5; ++i) {
        const float2 pv = p2[i];
        const float2 yv = y2[i];
        p[2 * i] = pv.x;
        p[2 * i + 1] = pv.y;
        y[2 * i] = yv.x;
        y[2 * i + 1] = yv.y;
      }
#pragma unroll
      for (int c = 0; c < 9; ++c) {
        sp[c] += p[c + 1];
        sl[c] += y[c + 1];
      }
      sy0 += y[0];
      sbce += -(y[0] * __logf(p[0]) + (1.0f - y[0]) * __logf(1.0f - p[0]));
    }
  }

  // Pack the 20 per-thread partials and reduce across the block.
  float vals[20];
#pragma unroll
  for (int c = 0; c < 9; ++c) {
    vals[c] = sp[c];
    vals[9 + c] = sl[c];
  }
  vals[18] = sy0;
  vals[19] = sbce;

#pragma unroll
  for (int i = 0; i < 20; ++i) {
    float v = vals[i];
#pragma unroll
    for (int off = 32; off > 0; off >>= 1) v += __shfl_down(v, off, 64);
    vals[i] = v;
  }

  __shared__ float lds[4][20];
  const int wave = threadIdx.x >> 6;
  const int lane = threadIdx.x & 63;
  if (lane == 0) {
#pragma unroll
    for (int i = 0; i < 20; ++i) lds[wave][i] = vals[i];
  }
  __syncthreads();
  if (threadIdx.x < 20) {
    const float v = lds[0][threadIdx.x] + lds[1][threadIdx.x] +
                    lds[2][threadIdx.x] + lds[3][threadIdx.x];
    // Private slot per (b, s): plain store, no zero-init required.
    row_acc[(b * SPLIT + s) * 20 + (int)threadIdx.x] = v;
  }
}

__global__ __launch_bounds__(128) void rsna_final_kernel(
    const float* __restrict__ row_acc, const int* __restrict__ seq_lens,
    float* __restrict__ out) {
  const int b = threadIdx.x;  // 0..127

  // Sum the SPLIT private slots for this row (each slot = 20 floats = 5xfloat4).
  float r[20];
#pragma unroll
  for (int i = 0; i < 20; ++i) r[i] = 0.0f;
  for (int s = 0; s < SPLIT; ++s) {
    const float4* seg =
        reinterpret_cast<const float4*>(row_acc + ((size_t)b * SPLIT + s) * 20);
#pragma unroll
    for (int j = 0; j < 5; ++j) {
      const float4 v = seg[j];
      r[4 * j + 0] += v.x;
      r[4 * j + 1] += v.y;
      r[4 * j + 2] += v.z;
      r[4 * j + 3] += v.w;
    }
  }

  const float len = (float)seq_lens[b];
  const float inv_len = 1.0f / len;

  float exam = 0.0f;
#pragma unroll
  for (int c = 0; c < 9; ++c) {
    const float pm = r[c] * inv_len;
    const float ym = r[9 + c] * inv_len;
    const float bce = -(ym * __logf(pm) + (1.0f - ym) * __logf(1.0f - pm));
    exam += EXAM_W[c] * bce;
  }
  const float sy0 = r[18];
  const float sbce = r[19];
  const float img_w = IMAGE_WEIGHT * sy0 * inv_len;  // IMAGE_WEIGHT * mean(y0)
  float numer = exam + sbce * img_w;                 // row's loss contribution
  float wext = IMAGE_WEIGHT * sy0;                   // img_w * len

#pragma unroll
  for (int off = 32; off > 0; off >>= 1) {
    numer += __shfl_down(numer, off, 64);
    wext += __shfl_down(wext, off, 64);
  }

  __shared__ float lds[4];
  if ((threadIdx.x & 63) == 0) {
    const int wave = threadIdx.x >> 6;
    lds[wave * 2] = numer;
    lds[wave * 2 + 1] = wext;
  }
  __syncthreads();
  if (threadIdx.x == 0) {
    float wsum = 0.0f;
#pragma unroll
    for (int c = 0; c < 9; ++c) wsum += EXAM_W[c];
    const float n = lds[0] + lds[2];
    const float w = lds[1] + lds[3];
    out[0] = n / ((float)B_DIM * wsum + w);
  }
}

extern "C" void kernel_launch(void* const* d_in, const int* in_sizes, int n_in,
                              void* d_out, int out_size, void* d_ws,
                              size_t ws_size, hipStream_t stream) {
  const float* pred = (const float*)d_in[0];
  const float* label = (const float*)d_in[1];
  const int* seq_lens = (const int*)d_in[2];
  float* row_acc = (float*)d_ws;  // 128*8*20 floats = 81920 B

  dim3 grid(B_DIM, SPLIT);
  rsna_partial_kernel<<<grid, 256, 0, stream>>>(pred, label, seq_lens, row_acc);
  rsna_final_kernel<<<1, 128, 0, stream>>>(row_acc, seq_lens, (float*)d_out);
}

// Round 3
// 111.282 us; speedup vs baseline: 1.0108x; 1.0108x over previous
//
#include <hip/hip_runtime.h>

// RSNA loss: pred/label [128, 8192, 10] fp32, seq_lens [128] i32 -> scalar fp32.
//
// Structure (2 dispatches, no memset, no atomics) — verified passing config:
//   kernel 1 (128 rows x SPLIT blocks, 256 thr): masked-prefix row sums ->
//     20 floats per (row, split) written to a PRIVATE slot of row_acc
//     (plain stores; no zeroed-workspace dependency, no atomics).
//     Records are 40 B; pairs of records (80 B) are 16B-aligned, so the
//     main loop does 5x float4 per array per 2 records (16 B/lane).
//   kernel 2 (1 block, 128 thr): sum the SPLIT slots per row, per-row
//     nonlinear part (exam BCE of means, image weighting) + final
//     reduction + division -> d_out[0].
//
// NOTE: hipLaunchCooperativeKernel is NOT graph-capturable in this harness
// (round-2 failure: launch silently dropped, out stayed 0). Keep plain
// stream launches.
//
// Only l < seq_lens[b] is ever read -> ~half the 84 MB input traffic.

#define L_DIM 8192
#define B_DIM 128
#define C_DIM 10
#define SPLIT 8

#define IMAGE_WEIGHT 0.0736196319f

__device__ __constant__ float EXAM_W[9] = {
    0.0736196319f, 0.09202453988f, 0.1042944785f, 0.1042944785f,
    0.1877300613f, 0.06257668712f, 0.06257668712f, 0.2346625767f,
    0.0782208589f};

__global__ __launch_bounds__(256) void rsna_partial_kernel(
    const float* __restrict__ pred, const float* __restrict__ label,
    const int* __restrict__ seq_lens, float* __restrict__ row_acc) {
  const int b = blockIdx.x;  // 0..127
  const int s = blockIdx.y;  // 0..SPLIT-1
  const int len = seq_lens[b];
  // Even chunk so every chunk start is an even record index -> 16B-aligned.
  int chunk = (len + SPLIT - 1) / SPLIT;
  chunk = (chunk + 1) & ~1;
  const int start = s * chunk;
  const int end = min(start + chunk, len);
  const int n = end - start;  // may be <= 0 for tail splits of short rows

  float sp[9], sl[9];
#pragma unroll
  for (int c = 0; c < 9; ++c) {
    sp[c] = 0.0f;
    sl[c] = 0.0f;
  }
  float sy0 = 0.0f;
  float sbce = 0.0f;

  if (n > 0) {
    const int npair = n >> 1;  // full record-pairs
    const size_t base = ((size_t)b * L_DIM + (size_t)start) * C_DIM;
    const float4* p4base = reinterpret_cast<const float4*>(pred + base);
    const float4* y4base = reinterpret_cast<const float4*>(label + base);

    for (int t = (int)threadIdx.x; t < npair; t += 256) {
      const float4* p4 = p4base + (size_t)t * 5;  // 80 B = 2 records
      const float4* y4 = y4base + (size_t)t * 5;
      float p[20], y[20];
#pragma unroll
      for (int j = 0; j < 5; ++j) {
        const float4 pv = p4[j];
        const float4 yv = y4[j];
        p[4 * j + 0] = pv.x;
        p[4 * j + 1] = pv.y;
        p[4 * j + 2] = pv.z;
        p[4 * j + 3] = pv.w;
        y[4 * j + 0] = yv.x;
        y[4 * j + 1] = yv.y;
        y[4 * j + 2] = yv.z;
        y[4 * j + 3] = yv.w;
      }
#pragma unroll
      for (int c = 0; c < 9; ++c) {
        sp[c] += p[c + 1] + p[c + 11];
        sl[c] += y[c + 1] + y[c + 11];
      }
      sy0 += y[0] + y[10];
      sbce += -(y[0] * __logf(p[0]) + (1.0f - y[0]) * __logf(1.0f - p[0]));
      sbce += -(y[10] * __logf(p[10]) + (1.0f - y[10]) * __logf(1.0f - p[10]));
    }

    // Odd tail record (at most one per block): handled by thread 0.
    if ((n & 1) && threadIdx.x == 0) {
      const int l = end - 1;
      const size_t tbase = ((size_t)b * L_DIM + (size_t)l) * C_DIM;
      const float2* p2 = reinterpret_cast<const float2*>(pred + tbase);
      const float2* y2 = reinterpret_cast<const float2*>(label + tbase);
      float p[10], y[10];
#pragma unroll
      for (int i = 0; i < 5; ++i) {
        const float2 pv = p2[i];
        const float2 yv = y2[i];
        p[2 * i] = pv.x;
        p[2 * i + 1] = pv.y;
        y[2 * i] = yv.x;
        y[2 * i + 1] = yv.y;
      }
#pragma unroll
      for (int c = 0; c < 9; ++c) {
        sp[c] += p[c + 1];
        sl[c] += y[c + 1];
      }
      sy0 += y[0];
      sbce += -(y[0] * __logf(p[0]) + (1.0f - y[0]) * __logf(1.0f - p[0]));
    }
  }

  // Pack the 20 per-thread partials and reduce across the block.
  float vals[20];
#pragma unroll
  for (int c = 0; c < 9; ++c) {
    vals[c] = sp[c];
    vals[9 + c] = sl[c];
  }
  vals[18] = sy0;
  vals[19] = sbce;

#pragma unroll
  for (int i = 0; i < 20; ++i) {
    float v = vals[i];
#pragma unroll
    for (int off = 32; off > 0; off >>= 1) v += __shfl_down(v, off, 64);
    vals[i] = v;
  }

  __shared__ float lds[4][20];
  const int wave = threadIdx.x >> 6;
  const int lane = threadIdx.x & 63;
  if (lane == 0) {
#pragma unroll
    for (int i = 0; i < 20; ++i) lds[wave][i] = vals[i];
  }
  __syncthreads();
  if (threadIdx.x < 20) {
    const float v = lds[0][threadIdx.x] + lds[1][threadIdx.x] +
                    lds[2][threadIdx.x] + lds[3][threadIdx.x];
    // Private slot per (b, s): plain store, no zero-init required.
    row_acc[(b * SPLIT + s) * 20 + (int)threadIdx.x] = v;
  }
}

__global__ __launch_bounds__(128) void rsna_final_kernel(
    const float* __restrict__ row_acc, const int* __restrict__ seq_lens,
    float* __restrict__ out) {
  const int b = threadIdx.x;  // 0..127

  // Sum the SPLIT private slots for this row (each slot = 20 floats = 5xfloat4).
  float r[20];
#pragma unroll
  for (int i = 0; i < 20; ++i) r[i] = 0.0f;
  for (int s = 0; s < SPLIT; ++s) {
    const float4* seg =
        reinterpret_cast<const float4*>(row_acc + ((size_t)b * SPLIT + s) * 20);
#pragma unroll
    for (int j = 0; j < 5; ++j) {
      const float4 v = seg[j];
      r[4 * j + 0] += v.x;
      r[4 * j + 1] += v.y;
      r[4 * j + 2] += v.z;
      r[4 * j + 3] += v.w;
    }
  }

  const float len = (float)seq_lens[b];
  const float inv_len = 1.0f / len;

  float exam = 0.0f;
#pragma unroll
  for (int c = 0; c < 9; ++c) {
    const float pm = r[c] * inv_len;
    const float ym = r[9 + c] * inv_len;
    const float bce = -(ym * __logf(pm) + (1.0f - ym) * __logf(1.0f - pm));
    exam += EXAM_W[c] * bce;
  }
  const float sy0 = r[18];
  const float sbce = r[19];
  const float img_w = IMAGE_WEIGHT * sy0 * inv_len;  // IMAGE_WEIGHT * mean(y0)
  float numer = exam + sbce * img_w;                 // row's loss contribution
  float wext = IMAGE_WEIGHT * sy0;                   // img_w * len

#pragma unroll
  for (int off = 32; off > 0; off >>= 1) {
    numer += __shfl_down(numer, off, 64);
    wext += __shfl_down(wext, off, 64);
  }

  __shared__ float lds[4];
  if ((threadIdx.x & 63) == 0) {
    const int wave = threadIdx.x >> 6;
    lds[wave * 2] = numer;
    lds[wave * 2 + 1] = wext;
  }
  __syncthreads();
  if (threadIdx.x == 0) {
    float wsum = 0.0f;
#pragma unroll
    for (int c = 0; c < 9; ++c) wsum += EXAM_W[c];
    const float n = lds[0] + lds[2];
    const float w = lds[1] + lds[3];
    out[0] = n / ((float)B_DIM * wsum + w);
  }
}

extern "C" void kernel_launch(void* const* d_in, const int* in_sizes, int n_in,
                              void* d_out, int out_size, void* d_ws,
                              size_t ws_size, hipStream_t stream) {
  const float* pred = (const float*)d_in[0];
  const float* label = (const float*)d_in[1];
  const int* seq_lens = (const int*)d_in[2];
  float* row_acc = (float*)d_ws;  // 128*8*20 floats = 81920 B

  dim3 grid(B_DIM, SPLIT);
  rsna_partial_kernel<<<grid, 256, 0, stream>>>(pred, label, seq_lens, row_acc);
  rsna_final_kernel<<<1, 128, 0, stream>>>(row_acc, seq_lens, (float*)d_out);
}